// Round 1
// baseline (9363.358 us; speedup 1.0000x reference)
//
#include <hip/hip_runtime.h>

// ---------------------------------------------------------------------------
// Fused MLP -> 2-layer LSTM scan (T=256) -> MLP head for MI355X (gfx950).
// One persistent kernel: 128 blocks x 512 threads; block owns 32 batch rows.
// GEMMs: v_mfma_f32_16x16x32_bf16 (f32 accum). c-state f32 in VGPRs.
// LSTM weights streamed from global (L2-resident, ~770KB total for all blocks).
// LDS tiles XOR-swizzled (granule ^ (row&7)) for conflict-free ds_read_b128.
// ---------------------------------------------------------------------------

typedef unsigned short u16;
typedef short bf16x8 __attribute__((ext_vector_type(8)));
typedef float f32x4 __attribute__((ext_vector_type(4)));

#define MFMA16(a, b, c) __builtin_amdgcn_mfma_f32_16x16x32_bf16((a), (b), (c), 0, 0, 0)

__device__ __forceinline__ u16 f2bf(float f) {
  union { float f; unsigned u; } v; v.f = f;
  unsigned r = (v.u + 0x7FFFu + ((v.u >> 16) & 1u)) >> 16;  // RNE
  return (u16)r;
}
__device__ __forceinline__ float fsig(float x) {
  return 1.0f / (1.0f + __expf(-x));
}
__device__ __forceinline__ float ftanh(float x) {
  return 2.0f / (1.0f + __expf(-2.0f * x)) - 1.0f;
}

// ---- workspace layout (u16 indices unless noted) --------------------------
// Wc1 [512][256] @ 0        : cat(Wih1, Whh1) along k
// Wc2 [512][256] @ 131072
// W1b [256][64]  @ 262144
// W2b [128][256] @ 278528
// W3b [128][128] @ 311296
// Wo1 [128][128] @ 327680
// Wo2 [256][128] @ 344064
// Wo3 [32][256]  @ 376832
// bs1 f32[512]   @ float-index 192512 (bih1+bhh1)
// bs2 f32[512]   @ float-index 193024
// total bytes: 774144

__global__ void prep_kernel(const float* __restrict__ Wih1, const float* __restrict__ Whh1,
                            const float* __restrict__ bih1, const float* __restrict__ bhh1,
                            const float* __restrict__ Wih2, const float* __restrict__ Whh2,
                            const float* __restrict__ bih2, const float* __restrict__ bhh2,
                            const float* __restrict__ W_in1, const float* __restrict__ W_in2,
                            const float* __restrict__ W_in3,
                            const float* __restrict__ W_out1, const float* __restrict__ W_out2,
                            const float* __restrict__ W_out3,
                            u16* __restrict__ ws) {
  const int N_total = 386048;
  int stride = gridDim.x * blockDim.x;
  for (int idx = blockIdx.x * blockDim.x + threadIdx.x; idx < N_total; idx += stride) {
    if (idx < 131072) {                       // Wc1
      int c = idx >> 8, k = idx & 255;
      float v = (k < 128) ? Wih1[c * 128 + k] : Whh1[c * 128 + (k - 128)];
      ws[idx] = f2bf(v);
    } else if (idx < 262144) {                // Wc2
      int i = idx - 131072; int c = i >> 8, k = i & 255;
      float v = (k < 128) ? Wih2[c * 128 + k] : Whh2[c * 128 + (k - 128)];
      ws[idx] = f2bf(v);
    } else if (idx < 278528) { ws[idx] = f2bf(W_in1[idx - 262144]);
    } else if (idx < 311296) { ws[idx] = f2bf(W_in2[idx - 278528]);
    } else if (idx < 327680) { ws[idx] = f2bf(W_in3[idx - 311296]);
    } else if (idx < 344064) { ws[idx] = f2bf(W_out1[idx - 327680]);
    } else if (idx < 376832) { ws[idx] = f2bf(W_out2[idx - 344064]);
    } else if (idx < 385024) { ws[idx] = f2bf(W_out3[idx - 376832]);
    } else if (idx < 385536) {                // bs1
      int i = idx - 385024;
      ((float*)ws)[192512 + i] = bih1[i] + bhh1[i];
    } else {                                  // bs2
      int i = idx - 385536;
      ((float*)ws)[193024 + i] = bih2[i] + bhh2[i];
    }
  }
}

__global__ __launch_bounds__(512, 1)
void lstm_fused(const float* __restrict__ seq,
                const float* __restrict__ h1_in, const float* __restrict__ c1_in,
                const float* __restrict__ h2_in, const float* __restrict__ c2_in,
                const float* __restrict__ b_in1, const float* __restrict__ b_in2,
                const float* __restrict__ b_in3,
                const float* __restrict__ b_out1, const float* __restrict__ b_out2,
                const float* __restrict__ b_out3,
                const u16* __restrict__ ws, float* __restrict__ out) {
  // LDS: 122,880 B total (<= 160 KiB): 1 block/CU.
  __shared__ u16 lds_W2[32768];     // [128][256] swizzled (W_in2, LDS-resident)
  __shared__ u16 lds_XB[2][4096];   // x_t double buffer [32][128]
  __shared__ u16 lds_H1[4096];      // h1 [32][128]
  __shared__ u16 lds_H2[4096];      // h2 [32][128]
  __shared__ u16 lds_F1[8192];      // fc mid [32][256], reused as Y2
  __shared__ u16 lds_F2[4096];      // fc mid [32][128], reused as Y1

  const int tid = threadIdx.x;
  const int wid = tid >> 6;         // wave 0..7
  const int lane = tid & 63;
  const int lr = lane & 15;         // A-row / B-col / D-col within 16-tile
  const int lg = lane >> 4;         // k-group; D rows = lg*4 + j
  const int b0 = blockIdx.x * 32;

  const u16* Wc1 = ws;
  const u16* Wc2 = ws + 131072;
  const u16* W1b = ws + 262144;
  const u16* W2b = ws + 278528;
  const u16* W3b = ws + 311296;
  const u16* Wo1 = ws + 327680;
  const u16* Wo2 = ws + 344064;
  const u16* Wo3 = ws + 376832;
  const float* bs1 = (const float*)ws + 192512;
  const float* bs2 = (const float*)ws + 193024;

  // ---- stage W_in2 into LDS (swizzled): 4096 granules of 16B ----
  {
#pragma unroll
    for (int i = 0; i < 8; ++i) {
      int gid = tid * 8 + i;                  // 0..4095
      int c = gid >> 5, k8 = gid & 31;        // col 0..127, k-granule 0..31
      bf16x8 v = *(const bf16x8*)(W2b + c * 256 + k8 * 8);
      *(bf16x8*)&lds_W2[((c * 32 + k8) ^ (c & 7)) * 8] = v;
    }
  }
  // ---- stage initial h1/h2 (f32 -> bf16, swizzled) ----
  {
    int idx = tid * 8;
    int r = idx >> 7;                          // 0..31
    int c8 = (idx & 127) >> 3;                 // 0..15
    const float* p1 = h1_in + (size_t)(b0 + r) * 128 + c8 * 8;
    const float* p2 = h2_in + (size_t)(b0 + r) * 128 + c8 * 8;
    bf16x8 v1, v2;
#pragma unroll
    for (int j = 0; j < 8; ++j) { v1[j] = (short)f2bf(p1[j]); v2[j] = (short)f2bf(p2[j]); }
    int g = ((r * 16 + c8) ^ (r & 7)) * 8;
    *(bf16x8*)&lds_H1[g] = v1;
    *(bf16x8*)&lds_H2[g] = v2;
  }
  // ---- c-state in registers: lane owns rows 16rt+lg*4+j, h-col 16*wid+lr ----
  float cs1[2][4], cs2[2][4];
#pragma unroll
  for (int rt = 0; rt < 2; ++rt)
#pragma unroll
    for (int j = 0; j < 4; ++j) {
      size_t off = (size_t)(b0 + 16 * rt + lg * 4 + j) * 128 + 16 * wid + lr;
      cs1[rt][j] = c1_in[off];
      cs2[rt][j] = c2_in[off];
    }
  // ---- biases (per-lane, hoisted) ----
  float bc1[4], bc2[4];
#pragma unroll
  for (int g = 0; g < 4; ++g) {
    bc1[g] = bs1[128 * g + 16 * wid + lr];
    bc2[g] = bs2[128 * g + 16 * wid + lr];
  }
  float bfc1[2] = { b_in1[32 * wid + lr], b_in1[32 * wid + 16 + lr] };
  float bfc2v = b_in2[16 * wid + lr];
  float bfc3v = b_in3[16 * wid + lr];
  __syncthreads();

  // ---- fc_in for timestep t1 -> lds_XB[db] -------------------------------
  auto fc_step = [&](int t1, int db) {
    // L1: [32,256] = relu(seq_t @ W1^T + b1), K=64. A from global f32.
    f32x4 acc[2][2] = {};
#pragma unroll
    for (int kt = 0; kt < 2; ++kt) {
      bf16x8 a[2];
#pragma unroll
      for (int rt = 0; rt < 2; ++rt) {
        const float* sp = seq + ((size_t)(b0 + 16 * rt + lr) * 256 + t1) * 64 + kt * 32 + lg * 8;
        float4 x0 = *(const float4*)sp;
        float4 x1 = *(const float4*)(sp + 4);
        bf16x8 av;
        av[0] = (short)f2bf(x0.x); av[1] = (short)f2bf(x0.y);
        av[2] = (short)f2bf(x0.z); av[3] = (short)f2bf(x0.w);
        av[4] = (short)f2bf(x1.x); av[5] = (short)f2bf(x1.y);
        av[6] = (short)f2bf(x1.z); av[7] = (short)f2bf(x1.w);
        a[rt] = av;
      }
#pragma unroll
      for (int ci = 0; ci < 2; ++ci) {
        bf16x8 b = *(const bf16x8*)(W1b + (size_t)(32 * wid + 16 * ci + lr) * 64 + kt * 32 + lg * 8);
        acc[0][ci] = MFMA16(a[0], b, acc[0][ci]);
        acc[1][ci] = MFMA16(a[1], b, acc[1][ci]);
      }
    }
#pragma unroll
    for (int rt = 0; rt < 2; ++rt)
#pragma unroll
      for (int ci = 0; ci < 2; ++ci)
#pragma unroll
        for (int j = 0; j < 4; ++j) {
          int r = 16 * rt + lg * 4 + j, c = 32 * wid + 16 * ci + lr;
          float v = fmaxf(acc[rt][ci][j] + bfc1[ci], 0.f);
          lds_F1[(r * 256 + c) ^ ((r & 7) << 3)] = f2bf(v);
        }
    __syncthreads();
    // L2: [32,128] = relu(F1 @ W2^T + b2), K=256. B from LDS.
    f32x4 ac2[2] = {};
#pragma unroll
    for (int kt = 0; kt < 8; ++kt) {
      bf16x8 a[2];
#pragma unroll
      for (int rt = 0; rt < 2; ++rt) {
        int r = 16 * rt + lr;
        a[rt] = *(const bf16x8*)&lds_F1[((r * 32 + kt * 4 + lg) ^ (r & 7)) * 8];
      }
      int cc = 16 * wid + lr;
      bf16x8 b = *(const bf16x8*)&lds_W2[((cc * 32 + kt * 4 + lg) ^ (cc & 7)) * 8];
      ac2[0] = MFMA16(a[0], b, ac2[0]);
      ac2[1] = MFMA16(a[1], b, ac2[1]);
    }
#pragma unroll
    for (int rt = 0; rt < 2; ++rt)
#pragma unroll
      for (int j = 0; j < 4; ++j) {
        int r = 16 * rt + lg * 4 + j, c = 16 * wid + lr;
        float v = fmaxf(ac2[rt][j] + bfc2v, 0.f);
        lds_F2[(r * 128 + c) ^ ((r & 7) << 3)] = f2bf(v);
      }
    __syncthreads();
    // L3: [32,128] = relu(F2 @ W3^T + b3), K=128 -> XB[db]
    f32x4 ac3[2] = {};
#pragma unroll
    for (int kt = 0; kt < 4; ++kt) {
      bf16x8 a[2];
#pragma unroll
      for (int rt = 0; rt < 2; ++rt) {
        int r = 16 * rt + lr;
        a[rt] = *(const bf16x8*)&lds_F2[((r * 16 + kt * 4 + lg) ^ (r & 7)) * 8];
      }
      bf16x8 b = *(const bf16x8*)(W3b + (size_t)(16 * wid + lr) * 128 + kt * 32 + lg * 8);
      ac3[0] = MFMA16(a[0], b, ac3[0]);
      ac3[1] = MFMA16(a[1], b, ac3[1]);
    }
#pragma unroll
    for (int rt = 0; rt < 2; ++rt)
#pragma unroll
      for (int j = 0; j < 4; ++j) {
        int r = 16 * rt + lg * 4 + j, c = 16 * wid + lr;
        float v = fmaxf(ac3[rt][j] + bfc3v, 0.f);
        lds_XB[db][(r * 128 + c) ^ ((r & 7) << 3)] = f2bf(v);
      }
    // no barrier here: next reader of XB[db] is separated by cell barriers
  };

  // ---- one LSTM cell: gates = [alo|ahi] @ W^T; updates cs; writes h->dst --
  auto cell = [&](const u16* alo, const u16* ahi, const u16* W,
                  const float* bc, float (&cs)[2][4], u16* dst) {
    f32x4 acc[2][4] = {};
#pragma unroll
    for (int kt = 0; kt < 8; ++kt) {
      const u16* ab = (kt < 4) ? alo : ahi;
      int k4 = (kt & 3) * 4 + lg;
      bf16x8 a[2];
#pragma unroll
      for (int rt = 0; rt < 2; ++rt) {
        int r = 16 * rt + lr;
        a[rt] = *(const bf16x8*)&ab[((r * 16 + k4) ^ (r & 7)) * 8];
      }
#pragma unroll
      for (int g = 0; g < 4; ++g) {
        bf16x8 b = *(const bf16x8*)(W + (size_t)(128 * g + 16 * wid + lr) * 256 + kt * 32 + lg * 8);
        acc[0][g] = MFMA16(a[0], b, acc[0][g]);
        acc[1][g] = MFMA16(a[1], b, acc[1][g]);
      }
    }
    float hv[2][4];
#pragma unroll
    for (int rt = 0; rt < 2; ++rt)
#pragma unroll
      for (int j = 0; j < 4; ++j) {
        float gi = acc[rt][0][j] + bc[0];
        float gf = acc[rt][1][j] + bc[1];
        float gg = acc[rt][2][j] + bc[2];
        float go = acc[rt][3][j] + bc[3];
        float cn = fsig(gf) * cs[rt][j] + fsig(gi) * ftanh(gg);
        cs[rt][j] = cn;
        hv[rt][j] = fsig(go) * ftanh(cn);
      }
    __syncthreads();   // all waves done reading old h before overwrite
#pragma unroll
    for (int rt = 0; rt < 2; ++rt)
#pragma unroll
      for (int j = 0; j < 4; ++j) {
        int r = 16 * rt + lg * 4 + j;
        dst[(r * 128 + 16 * wid + lr) ^ ((r & 7) << 3)] = f2bf(hv[rt][j]);
      }
    __syncthreads();
  };

  // ---- scan ----
  fc_step(0, 0);
  __syncthreads();
  for (int t = 0; t < 256; ++t) {
    int cur = t & 1;
    if (t + 1 < 256) fc_step(t + 1, cur ^ 1);
    cell(lds_XB[cur], lds_H1, Wc1, bc1, cs1, lds_H1);   // cell1: x_t | h1
    cell(lds_H1, lds_H2, Wc2, bc2, cs2, lds_H2);        // cell2: h1  | h2
  }

  // ---- fc_out head ----
  { // Y1 = relu(h2 @ Wo1^T + b_out1): [32,128], K=128 -> lds_F2
    f32x4 acc[2] = {};
#pragma unroll
    for (int kt = 0; kt < 4; ++kt) {
      bf16x8 a[2];
#pragma unroll
      for (int rt = 0; rt < 2; ++rt) {
        int r = 16 * rt + lr;
        a[rt] = *(const bf16x8*)&lds_H2[((r * 16 + kt * 4 + lg) ^ (r & 7)) * 8];
      }
      bf16x8 b = *(const bf16x8*)(Wo1 + (size_t)(16 * wid + lr) * 128 + kt * 32 + lg * 8);
      acc[0] = MFMA16(a[0], b, acc[0]);
      acc[1] = MFMA16(a[1], b, acc[1]);
    }
    float bo1v = b_out1[16 * wid + lr];
#pragma unroll
    for (int rt = 0; rt < 2; ++rt)
#pragma unroll
      for (int j = 0; j < 4; ++j) {
        int r = 16 * rt + lg * 4 + j, c = 16 * wid + lr;
        lds_F2[(r * 128 + c) ^ ((r & 7) << 3)] = f2bf(fmaxf(acc[rt][j] + bo1v, 0.f));
      }
    __syncthreads();
  }
  { // Y2 = relu(Y1 @ Wo2^T + b_out2): [32,256], K=128 -> lds_F1
    f32x4 acc[2][2] = {};
#pragma unroll
    for (int kt = 0; kt < 4; ++kt) {
      bf16x8 a[2];
#pragma unroll
      for (int rt = 0; rt < 2; ++rt) {
        int r = 16 * rt + lr;
        a[rt] = *(const bf16x8*)&lds_F2[((r * 16 + kt * 4 + lg) ^ (r & 7)) * 8];
      }
#pragma unroll
      for (int ci = 0; ci < 2; ++ci) {
        bf16x8 b = *(const bf16x8*)(Wo2 + (size_t)(32 * wid + 16 * ci + lr) * 128 + kt * 32 + lg * 8);
        acc[0][ci] = MFMA16(a[0], b, acc[0][ci]);
        acc[1][ci] = MFMA16(a[1], b, acc[1][ci]);
      }
    }
#pragma unroll
    for (int rt = 0; rt < 2; ++rt)
#pragma unroll
      for (int ci = 0; ci < 2; ++ci)
#pragma unroll
        for (int j = 0; j < 4; ++j) {
          int r = 16 * rt + lg * 4 + j, c = 32 * wid + 16 * ci + lr;
          float v = fmaxf(acc[rt][ci][j] + b_out2[c], 0.f);
          lds_F1[(r * 256 + c) ^ ((r & 7) << 3)] = f2bf(v);
        }
    __syncthreads();
  }
  if (wid < 4) { // Y3 = Y2 @ Wo3^T + b_out3: [32,32], K=256; waves 0..3
    int rt = wid >> 1, ci = wid & 1;
    f32x4 acc = {};
#pragma unroll
    for (int kt = 0; kt < 8; ++kt) {
      int r = 16 * rt + lr;
      bf16x8 a = *(const bf16x8*)&lds_F1[((r * 32 + kt * 4 + lg) ^ (r & 7)) * 8];
      bf16x8 b = *(const bf16x8*)(Wo3 + (size_t)(16 * ci + lr) * 256 + kt * 32 + lg * 8);
      acc = MFMA16(a, b, acc);
    }
    float bo3v = b_out3[16 * ci + lr];
#pragma unroll
    for (int j = 0; j < 4; ++j)
      out[(size_t)(b0 + 16 * rt + lg * 4 + j) * 32 + 16 * ci + lr] = acc[j] + bo3v;
  }
}

extern "C" void kernel_launch(void* const* d_in, const int* in_sizes, int n_in,
                              void* d_out, int out_size, void* d_ws, size_t ws_size,
                              hipStream_t stream) {
  (void)in_sizes; (void)n_in; (void)out_size; (void)ws_size;
  const float* seq    = (const float*)d_in[0];
  const float* h1     = (const float*)d_in[1];
  const float* c1     = (const float*)d_in[2];
  const float* h2     = (const float*)d_in[3];
  const float* c2     = (const float*)d_in[4];
  const float* W_in1  = (const float*)d_in[5];
  const float* b_in1  = (const float*)d_in[6];
  const float* W_in2  = (const float*)d_in[7];
  const float* b_in2  = (const float*)d_in[8];
  const float* W_in3  = (const float*)d_in[9];
  const float* b_in3  = (const float*)d_in[10];
  const float* Wih1   = (const float*)d_in[11];
  const float* Whh1   = (const float*)d_in[12];
  const float* bih1   = (const float*)d_in[13];
  const float* bhh1   = (const float*)d_in[14];
  const float* Wih2   = (const float*)d_in[15];
  const float* Whh2   = (const float*)d_in[16];
  const float* bih2   = (const float*)d_in[17];
  const float* bhh2   = (const float*)d_in[18];
  const float* W_out1 = (const float*)d_in[19];
  const float* b_out1 = (const float*)d_in[20];
  const float* W_out2 = (const float*)d_in[21];
  const float* b_out2 = (const float*)d_in[22];
  const float* W_out3 = (const float*)d_in[23];
  const float* b_out3 = (const float*)d_in[24];
  u16* ws = (u16*)d_ws;
  float* out = (float*)d_out;

  hipLaunchKernelGGL(prep_kernel, dim3(512), dim3(256), 0, stream,
                     Wih1, Whh1, bih1, bhh1, Wih2, Whh2, bih2, bhh2,
                     W_in1, W_in2, W_in3, W_out1, W_out2, W_out3, ws);
  hipLaunchKernelGGL(lstm_fused, dim3(128), dim3(512), 0, stream,
                     seq, h1, c1, h2, c2, b_in1, b_in2, b_in3,
                     b_out1, b_out2, b_out3, ws, out);
}